// Round 16
// baseline (69.261 us; speedup 1.0000x reference)
//
#include <hip/hip_runtime.h>

#define N_NODES 50000
#define N_EDGES 800000
#define D_IN    128
#define CAP     64      // max degree ~40 for Binomial(800k, 1/50k)

#define NBKT    782     // ceil(50000/64) buckets of 64 nodes (bucket = dst>>6)
#define BCAP    1280    // per-bucket staging cap (mean 1024, sd 32, +8 sigma)
#define EPT     16      // edges per thread in k_split
#define EPB     (256 * EPT)                        // 4096 edges per split block
#define SPLIT_BLOCKS ((N_EDGES + EPB - 1) / EPB)   // 196
#define CVT_BLOCKS   ((N_NODES * 64 + 255) / 256)  // 12500

// ---------------------------------------------------------------------------
// Round 16: fuse build+agg, shrink buckets 256->64 nodes.
//   k_split_cvt : edges read ONCE; LDS histogram over 782 buckets; 1 global
//                 atomic per (block,bucket); clustered record stores. cvt fused.
//   k_bagg      : 782 blocks. Phase A: build 64-node segments in LDS
//                 (8KB, LDS atomics). Phase B: 4 waves x 16 nodes, neighbor
//                 ids read from LDS (uniform broadcast), 8-deep MLP gather,
//                 fused W_l dot + selfdot. No sorted16/cnt round-trip.
//
// ws: gctr[1024] 4KB | staging[782*1280] u32 4MB | Xh[N*128] u16 12.8MB |
//     selfdot[N] f32 200KB   (~17 MB total)
// ---------------------------------------------------------------------------

__device__ __forceinline__ unsigned short f32_to_bf16_rn(float f) {
    unsigned int u = __float_as_uint(f);
    u += 0x7fffu + ((u >> 16) & 1u);      // round-to-nearest-even
    return (unsigned short)(u >> 16);
}

__global__ __launch_bounds__(256) void k_zero(int* __restrict__ gctr)
{
    int i = blockIdx.x * 256 + threadIdx.x;
    if (i < NBKT) gctr[i] = 0;
}

__global__ __launch_bounds__(256) void k_split_cvt(
    const int*   __restrict__ src,
    const int*   __restrict__ dst,
    int*         __restrict__ gctr,
    unsigned int* __restrict__ staging,
    const float* __restrict__ X,
    const float* __restrict__ W_r,
    const float* __restrict__ b_l,
    unsigned short* __restrict__ Xh,
    float*       __restrict__ selfdot)
{
    int b = blockIdx.x;
    if (b < SPLIT_BLOCKS) {
        __shared__ int hist[NBKT];
        __shared__ int base[NBKT];
        int tid = threadIdx.x;
        for (int i = tid; i < NBKT; i += 256) hist[i] = 0;
        __syncthreads();

        int t[EPT], s[EPT], bk[EPT];
        bool ok[EPT];
        int e0 = b * EPB + tid;
#pragma unroll
        for (int k = 0; k < EPT; ++k) {
            int e = e0 + (k << 8);
            bool v = e < N_EDGES;
            int ec = v ? e : 0;
            t[k] = dst[ec]; s[k] = src[ec];
            bk[k] = t[k] >> 6;
            ok[k] = v;
            if (v) atomicAdd(&hist[bk[k]], 1);     // fire-and-forget LDS add
        }
        __syncthreads();
        for (int i = tid; i < NBKT; i += 256) {
            int h = hist[i];
            base[i] = h ? atomicAdd(&gctr[i], h) : 0;   // 1 global atomic/bucket
            hist[i] = 0;                                 // reuse as cursor
        }
        __syncthreads();
#pragma unroll
        for (int k = 0; k < EPT; ++k) {
            if (ok[k]) {
                int pos = base[bk[k]] + atomicAdd(&hist[bk[k]], 1);
                if (pos < BCAP)
                    staging[(size_t)bk[k] * BCAP + pos] =
                        ((unsigned int)(t[k] & 63) << 16) | (unsigned int)s[k];
            }
        }
        return;
    }
    // cvt role: one wave per row -> bf16 row + selfdot = W_r.x + b_l
    int wave = ((b - SPLIT_BLOCKS) * 256 + threadIdx.x) >> 6;
    int lane = threadIdx.x & 63;
    if (wave >= N_NODES) return;

    float2 x = ((const float2*)(X + (size_t)wave * D_IN))[lane];
    unsigned int packed = ((unsigned int)f32_to_bf16_rn(x.y) << 16)
                        |  (unsigned int)f32_to_bf16_rn(x.x);
    ((unsigned int*)(Xh + (size_t)wave * D_IN))[lane] = packed;

    float2 wr = ((const float2*)W_r)[lane];
    float acc = x.x * wr.x + x.y * wr.y;
#pragma unroll
    for (int off = 32; off; off >>= 1)
        acc += __shfl_down(acc, off);
    if (lane == 0)
        selfdot[wave] = acc + b_l[0];
}

#define GATHER(mm, ss)                                                \
    {                                                                 \
        unsigned int u = Xu[(size_t)(ss) * 64 + lane];                \
        (mm).x = fmaxf((mm).x, __uint_as_float(u << 16));             \
        (mm).y = fmaxf((mm).y, __uint_as_float(u & 0xffff0000u));     \
    }
#define GB(K, I)                                                      \
    {                                                                 \
        int sr[K];                                                    \
        _Pragma("unroll")                                             \
        for (int k = 0; k < K; ++k) sr[k] = seg[(I) + k];             \
        _Pragma("unroll")                                             \
        for (int k = 0; k < K; ++k) GATHER(m[k], sr[k])               \
    }

// Fused build+aggregate: one block per 64-node bucket.
__global__ __launch_bounds__(256) void k_bagg(
    const unsigned int* __restrict__ staging,
    const int*   __restrict__ gctr,
    const unsigned short* __restrict__ Xh,
    const float* __restrict__ W_l,
    const float* __restrict__ selfdot,
    float*       __restrict__ out)
{
    __shared__ unsigned short lbuf[64 * CAP];   // 8 KB
    __shared__ int lcnt[64];
    int b   = blockIdx.x;
    int tid = threadIdx.x;
    if (tid < 64) lcnt[tid] = 0;
    __syncthreads();

    // Phase A: build per-node segments in LDS
    int count = gctr[b];
    if (count > BCAP) count = BCAP;
    for (int i = tid; i < count; i += 256) {
        unsigned int rec = staging[(size_t)b * BCAP + i];
        int nlo = rec >> 16;
        int pos = atomicAdd(&lcnt[nlo], 1);
        if (pos < CAP)
            lbuf[nlo * CAP + pos] = (unsigned short)(rec & 0xffffu);
    }
    __syncthreads();

    // Phase B: 4 waves x 16 nodes each, gather + fused dot
    int wid  = tid >> 6;
    int lane = tid & 63;
    float2 wl = ((const float2*)W_l)[lane];
    const unsigned int* Xu = (const unsigned int*)Xh;

    for (int j = 0; j < 16; ++j) {
        int li   = (wid << 4) + j;
        int node = (b << 6) + li;
        if (node >= N_NODES) return;            // uniform per wave (no barriers left)
        float sd = selfdot[node];               // prefetch, overlaps gathers
        int n = lcnt[li];
        if (n > CAP) n = CAP;
        const unsigned short* seg = &lbuf[li * CAP];

        float2 m[8];
#pragma unroll
        for (int k = 0; k < 8; ++k) m[k] = make_float2(-INFINITY, -INFINITY);

        int i = 0;
        for (; i + 8 <= n; i += 8) GB(8, i)
        if (i + 4 <= n) { GB(4, i) i += 4; }
        if (i + 2 <= n) { GB(2, i) i += 2; }
        if (i < n)      { GB(1, i) }

#pragma unroll
        for (int k = 4; k; k >>= 1)
#pragma unroll
            for (int q = 0; q < k; ++q) {
                m[q].x = fmaxf(m[q].x, m[q + k].x);
                m[q].y = fmaxf(m[q].y, m[q + k].y);
            }
        if (n == 0) { m[0].x = 0.0f; m[0].y = 0.0f; }   // segment_max empty fill

        float acc = m[0].x * wl.x + m[0].y * wl.y;
#pragma unroll
        for (int off = 32; off; off >>= 1)
            acc += __shfl_down(acc, off);
        if (lane == 0)
            out[node] = acc + sd;
    }
}

extern "C" void kernel_launch(void* const* d_in, const int* in_sizes, int n_in,
                              void* d_out, int out_size, void* d_ws, size_t ws_size,
                              hipStream_t stream)
{
    const float* X   = (const float*)d_in[0];   // [N_NODES, D_IN]
    const float* W_l = (const float*)d_in[1];   // [1, D_IN]
    const float* b_l = (const float*)d_in[2];   // [1]
    const float* W_r = (const float*)d_in[3];   // [1, D_IN]
    const int*   ei  = (const int*)d_in[4];     // [2, N_EDGES]
    const int*   src = ei;
    const int*   dst = ei + N_EDGES;

    int* gctr = (int*)d_ws;                                         // 4 KB (1024 ints)
    unsigned int* staging = (unsigned int*)(gctr + 1024);           // 4.0 MB
    unsigned short* Xh = (unsigned short*)(staging + (size_t)NBKT * BCAP); // 12.8 MB
    float* selfdot = (float*)(Xh + (size_t)N_NODES * D_IN);         // 200 KB
    float* out = (float*)d_out;

    k_zero<<<(NBKT + 255) / 256, 256, 0, stream>>>(gctr);
    k_split_cvt<<<SPLIT_BLOCKS + CVT_BLOCKS, 256, 0, stream>>>(
        src, dst, gctr, staging, X, W_r, b_l, Xh, selfdot);
    k_bagg<<<NBKT, 256, 0, stream>>>(staging, gctr, Xh, W_l, selfdot, out);
}

// Round 17
// 64.971 us; speedup vs baseline: 1.0660x; 1.0660x over previous
//
#include <hip/hip_runtime.h>

#define N_NODES 50000
#define N_EDGES 800000
#define D_IN    128
#define CAP     64      // max degree ~40 for Binomial(800k, 1/50k)

#define NBKT    782     // ceil(50000/64) buckets of 64 nodes (bucket = dst>>6)
#define BCAP    1280    // per-bucket staging cap (mean 1024, sd 32, +8 sigma)
#define EPT     16      // edges per thread in k_split
#define EPB     (256 * EPT)                        // 4096 edges per split block
#define SPLIT_BLOCKS ((N_EDGES + EPB - 1) / EPB)   // 196
#define CVT_BLOCKS   ((N_NODES * 64 + 255) / 256)  // 12500

// ---------------------------------------------------------------------------
// Round 17 = round 15 pipeline (67.4us best) with 64-node build buckets:
//   k_split_cvt : edges read ONCE; LDS histogram over 782 buckets; 1 global
//                 atomic per (block,bucket); clustered stores. cvt fused.
//   k_build     : 782 blocks (was 196 — <1/CU was the build bottleneck),
//                 8KB LDS segments, coalesced dword write-out of rows+cnt.
//   k_agg       : separate (round-16 fusion collapsed occupancy 65->23%),
//                 8-deep MLP gather, fused dots.
//
// ws: gctr[1024] 4KB | staging[782*1280] u32 4MB | cnt[N] 200KB |
//     sorted16[N*CAP] u16 6.4MB | Xh[N*128] u16 12.8MB | selfdot[N] 200KB
// ---------------------------------------------------------------------------

__device__ __forceinline__ unsigned short f32_to_bf16_rn(float f) {
    unsigned int u = __float_as_uint(f);
    u += 0x7fffu + ((u >> 16) & 1u);      // round-to-nearest-even
    return (unsigned short)(u >> 16);
}

__global__ __launch_bounds__(256) void k_zero(int* __restrict__ gctr)
{
    int i = blockIdx.x * 256 + threadIdx.x;
    if (i < NBKT) gctr[i] = 0;
}

__global__ __launch_bounds__(256) void k_split_cvt(
    const int*   __restrict__ src,
    const int*   __restrict__ dst,
    int*         __restrict__ gctr,
    unsigned int* __restrict__ staging,
    const float* __restrict__ X,
    const float* __restrict__ W_r,
    const float* __restrict__ b_l,
    unsigned short* __restrict__ Xh,
    float*       __restrict__ selfdot)
{
    int b = blockIdx.x;
    if (b < SPLIT_BLOCKS) {
        __shared__ int hist[NBKT];
        __shared__ int base[NBKT];
        int tid = threadIdx.x;
        for (int i = tid; i < NBKT; i += 256) hist[i] = 0;
        __syncthreads();

        int t[EPT], s[EPT], bk[EPT];
        bool ok[EPT];
        int e0 = b * EPB + tid;
#pragma unroll
        for (int k = 0; k < EPT; ++k) {
            int e = e0 + (k << 8);
            bool v = e < N_EDGES;
            int ec = v ? e : 0;
            t[k] = dst[ec]; s[k] = src[ec];
            bk[k] = t[k] >> 6;
            ok[k] = v;
            if (v) atomicAdd(&hist[bk[k]], 1);     // fire-and-forget LDS add
        }
        __syncthreads();
        for (int i = tid; i < NBKT; i += 256) {
            int h = hist[i];
            base[i] = h ? atomicAdd(&gctr[i], h) : 0;   // 1 global atomic/bucket
            hist[i] = 0;                                 // reuse as cursor
        }
        __syncthreads();
#pragma unroll
        for (int k = 0; k < EPT; ++k) {
            if (ok[k]) {
                int pos = base[bk[k]] + atomicAdd(&hist[bk[k]], 1);
                if (pos < BCAP)
                    staging[(size_t)bk[k] * BCAP + pos] =
                        ((unsigned int)(t[k] & 63) << 16) | (unsigned int)s[k];
            }
        }
        return;
    }
    // cvt role: one wave per row -> bf16 row + selfdot = W_r.x + b_l
    int wave = ((b - SPLIT_BLOCKS) * 256 + threadIdx.x) >> 6;
    int lane = threadIdx.x & 63;
    if (wave >= N_NODES) return;

    float2 x = ((const float2*)(X + (size_t)wave * D_IN))[lane];
    unsigned int packed = ((unsigned int)f32_to_bf16_rn(x.y) << 16)
                        |  (unsigned int)f32_to_bf16_rn(x.x);
    ((unsigned int*)(Xh + (size_t)wave * D_IN))[lane] = packed;

    float2 wr = ((const float2*)W_r)[lane];
    float acc = x.x * wr.x + x.y * wr.y;
#pragma unroll
    for (int off = 32; off; off >>= 1)
        acc += __shfl_down(acc, off);
    if (lane == 0)
        selfdot[wave] = acc + b_l[0];
}

// One block per 64-node bucket: LDS per-node segments, coalesced write-out.
__global__ __launch_bounds__(256) void k_build(
    const unsigned int* __restrict__ staging,
    const int*   __restrict__ gctr,
    int*         __restrict__ cnt,
    unsigned short* __restrict__ sorted16)
{
    __shared__ unsigned short lbuf[64 * CAP];   // 8 KB
    __shared__ int lcnt[64];
    int b   = blockIdx.x;        // bucket
    int tid = threadIdx.x;
    if (tid < 64) lcnt[tid] = 0;
    __syncthreads();

    int count = gctr[b];
    if (count > BCAP) count = BCAP;
    for (int i = tid; i < count; i += 256) {
        unsigned int rec = staging[(size_t)b * BCAP + i];
        int nlo = rec >> 16;
        int pos = atomicAdd(&lcnt[nlo], 1);
        if (pos < CAP)
            lbuf[nlo * CAP + pos] = (unsigned short)(rec & 0xffffu);
    }
    __syncthreads();

    int nodebase = b << 6;
    if (tid < 64) {
        int node = nodebase + tid;
        if (node < N_NODES) {
            int c = lcnt[tid];
            cnt[node] = c < CAP ? c : CAP;
        }
    }
    int nrows = N_NODES - nodebase;
    if (nrows > 64) nrows = 64;
    int tot32 = nrows * (CAP / 2);               // dwords to copy
    const unsigned int* lb32 = (const unsigned int*)lbuf;
    unsigned int* out32 = (unsigned int*)(sorted16 + (size_t)nodebase * CAP);
    for (int i = tid; i < tot32; i += 256)
        out32[i] = lb32[i];                      // garbage tails never read
}

#define GATHER(mm, ss)                                                \
    {                                                                 \
        unsigned int u = Xu[(size_t)(ss) * 64 + lane];                \
        (mm).x = fmaxf((mm).x, __uint_as_float(u << 16));             \
        (mm).y = fmaxf((mm).y, __uint_as_float(u & 0xffff0000u));     \
    }

// One wave per node. 8 independent gathers in flight (MLP), 4/2/1 tail.
__global__ __launch_bounds__(256) void k_agg(
    const unsigned short* __restrict__ Xh,
    const int*   __restrict__ cnt,
    const unsigned short* __restrict__ sorted16,
    const float* __restrict__ W_l,
    const float* __restrict__ selfdot,
    float*       __restrict__ out)
{
    int wave = (blockIdx.x * 256 + threadIdx.x) >> 6;
    int lane = threadIdx.x & 63;
    if (wave >= N_NODES) return;

    // independent loads -> both in flight together
    int n = cnt[wave];
    int sid = (int)sorted16[wave * CAP + lane];   // lanes >= n never consumed
    if (n > CAP) n = CAP;

    float2 wl = ((const float2*)W_l)[lane];   // hoisted: overlaps gather latency
    float sd  = selfdot[wave];

    const unsigned int* Xu = (const unsigned int*)Xh;
    float2 m[8];
#pragma unroll
    for (int k = 0; k < 8; ++k) m[k] = make_float2(-INFINITY, -INFINITY);

    int i = 0;
    for (; i + 8 <= n; i += 8) {
        int s0 = __shfl(sid, i + 0), s1 = __shfl(sid, i + 1);
        int s2 = __shfl(sid, i + 2), s3 = __shfl(sid, i + 3);
        int s4 = __shfl(sid, i + 4), s5 = __shfl(sid, i + 5);
        int s6 = __shfl(sid, i + 6), s7 = __shfl(sid, i + 7);
        GATHER(m[0], s0) GATHER(m[1], s1) GATHER(m[2], s2) GATHER(m[3], s3)
        GATHER(m[4], s4) GATHER(m[5], s5) GATHER(m[6], s6) GATHER(m[7], s7)
    }
    if (i + 4 <= n) {
        int s0 = __shfl(sid, i + 0), s1 = __shfl(sid, i + 1);
        int s2 = __shfl(sid, i + 2), s3 = __shfl(sid, i + 3);
        GATHER(m[0], s0) GATHER(m[1], s1) GATHER(m[2], s2) GATHER(m[3], s3)
        i += 4;
    }
    if (i + 2 <= n) {
        int s0 = __shfl(sid, i + 0), s1 = __shfl(sid, i + 1);
        GATHER(m[0], s0) GATHER(m[1], s1)
        i += 2;
    }
    if (i < n) {
        int s0 = __shfl(sid, i);
        GATHER(m[0], s0)
    }
#pragma unroll
    for (int k = 4; k; k >>= 1)
#pragma unroll
        for (int j = 0; j < k; ++j) {
            m[j].x = fmaxf(m[j].x, m[j + k].x);
            m[j].y = fmaxf(m[j].y, m[j + k].y);
        }
    if (n == 0) { m[0].x = 0.0f; m[0].y = 0.0f; }   // segment_max empty fill

    float acc = m[0].x * wl.x + m[0].y * wl.y;
#pragma unroll
    for (int off = 32; off; off >>= 1)
        acc += __shfl_down(acc, off);
    if (lane == 0)
        out[wave] = acc + sd;
}

extern "C" void kernel_launch(void* const* d_in, const int* in_sizes, int n_in,
                              void* d_out, int out_size, void* d_ws, size_t ws_size,
                              hipStream_t stream)
{
    const float* X   = (const float*)d_in[0];   // [N_NODES, D_IN]
    const float* W_l = (const float*)d_in[1];   // [1, D_IN]
    const float* b_l = (const float*)d_in[2];   // [1]
    const float* W_r = (const float*)d_in[3];   // [1, D_IN]
    const int*   ei  = (const int*)d_in[4];     // [2, N_EDGES]
    const int*   src = ei;
    const int*   dst = ei + N_EDGES;

    int* gctr = (int*)d_ws;                                         // 4 KB (1024 ints)
    unsigned int* staging = (unsigned int*)(gctr + 1024);           // 4.0 MB
    int* cnt = (int*)(staging + (size_t)NBKT * BCAP);               // 200 KB
    unsigned short* sorted16 = (unsigned short*)(cnt + N_NODES);    // 6.4 MB
    unsigned short* Xh = sorted16 + (size_t)N_NODES * CAP;          // 12.8 MB
    float* selfdot = (float*)(Xh + (size_t)N_NODES * D_IN);         // 200 KB
    float* out = (float*)d_out;

    k_zero<<<(NBKT + 255) / 256, 256, 0, stream>>>(gctr);
    k_split_cvt<<<SPLIT_BLOCKS + CVT_BLOCKS, 256, 0, stream>>>(
        src, dst, gctr, staging, X, W_r, b_l, Xh, selfdot);
    k_build<<<NBKT, 256, 0, stream>>>(staging, gctr, cnt, sorted16);
    k_agg<<<(N_NODES * 64 + 255) / 256, 256, 0, stream>>>(
        Xh, cnt, sorted16, W_l, selfdot, out);
}

// Round 18
// 64.067 us; speedup vs baseline: 1.0811x; 1.0141x over previous
//
#include <hip/hip_runtime.h>

#define N_NODES 50000
#define N_EDGES 800000
#define D_IN    128
#define CAP     64      // max degree ~40 for Binomial(800k, 1/50k)

#define NBKT    782     // ceil(50000/64) buckets of 64 nodes (bucket = dst>>6)
#define BCAP    1280    // per-bucket staging cap (mean 1024, sd 32, +8 sigma)
#define EPT     16      // edges per thread in k_split
#define EPB     (256 * EPT)                        // 4096 edges per split block
#define SPLIT_BLOCKS ((N_EDGES + EPB - 1) / EPB)   // 196 (800000/4096=195.3 -> 196)
#define CVT_BLOCKS   ((N_NODES * 64 + 255) / 256)  // 12500

// ---------------------------------------------------------------------------
// Round 18 = round 17 (65.0us best) + two isolated tweaks:
//   1. k_agg: 16 gathers in flight (fold into m[8] to cap VGPR ~48) — avg
//      degree 16 means the typical node now completes in ONE latency round.
//      (Round 7's "16-deep regression" was confounded by NT-store L2 poison.)
//   2. k_split_cvt: int4 edge loads (4 edges / 16B per lane).
//
// ws: gctr[1024] 4KB | staging[782*1280] u32 4MB | cnt[N] 200KB |
//     sorted16[N*CAP] u16 6.4MB | Xh[N*128] u16 12.8MB | selfdot[N] 200KB
// ---------------------------------------------------------------------------

__device__ __forceinline__ unsigned short f32_to_bf16_rn(float f) {
    unsigned int u = __float_as_uint(f);
    u += 0x7fffu + ((u >> 16) & 1u);      // round-to-nearest-even
    return (unsigned short)(u >> 16);
}

__global__ __launch_bounds__(256) void k_zero(int* __restrict__ gctr)
{
    int i = blockIdx.x * 256 + threadIdx.x;
    if (i < NBKT) gctr[i] = 0;
}

__global__ __launch_bounds__(256) void k_split_cvt(
    const int*   __restrict__ src,
    const int*   __restrict__ dst,
    int*         __restrict__ gctr,
    unsigned int* __restrict__ staging,
    const float* __restrict__ X,
    const float* __restrict__ W_r,
    const float* __restrict__ b_l,
    unsigned short* __restrict__ Xh,
    float*       __restrict__ selfdot)
{
    int b = blockIdx.x;
    if (b < SPLIT_BLOCKS) {
        __shared__ int hist[NBKT];
        __shared__ int base[NBKT];
        int tid = threadIdx.x;
        for (int i = tid; i < NBKT; i += 256) hist[i] = 0;
        __syncthreads();

        // int4 edge loads: block covers 1024 int4s (=4096 edges).
        // Thread tid handles int4 slots {tid, tid+256, tid+512, tid+768}.
        int t[EPT], s[EPT], bk[EPT];
        bool ok[EPT];
        const int4* d4 = (const int4*)dst;
        const int4* s4 = (const int4*)src;
        int q0 = b * (EPB / 4) + tid;
#pragma unroll
        for (int k = 0; k < 4; ++k) {
            int q = q0 + (k << 8);                     // int4 index
            bool v = (q * 4) < N_EDGES;                // whole int4 valid (N_EDGES%4==0)
            int qc = v ? q : 0;
            int4 dv = d4[qc];
            int4 sv = s4[qc];
            t[k*4+0] = dv.x; t[k*4+1] = dv.y; t[k*4+2] = dv.z; t[k*4+3] = dv.w;
            s[k*4+0] = sv.x; s[k*4+1] = sv.y; s[k*4+2] = sv.z; s[k*4+3] = sv.w;
            ok[k*4+0] = ok[k*4+1] = ok[k*4+2] = ok[k*4+3] = v;
        }
#pragma unroll
        for (int k = 0; k < EPT; ++k) {
            bk[k] = t[k] >> 6;
            if (ok[k]) atomicAdd(&hist[bk[k]], 1);     // fire-and-forget LDS add
        }
        __syncthreads();
        for (int i = tid; i < NBKT; i += 256) {
            int h = hist[i];
            base[i] = h ? atomicAdd(&gctr[i], h) : 0;  // 1 global atomic/bucket
            hist[i] = 0;                               // reuse as cursor
        }
        __syncthreads();
#pragma unroll
        for (int k = 0; k < EPT; ++k) {
            if (ok[k]) {
                int pos = base[bk[k]] + atomicAdd(&hist[bk[k]], 1);
                if (pos < BCAP)
                    staging[(size_t)bk[k] * BCAP + pos] =
                        ((unsigned int)(t[k] & 63) << 16) | (unsigned int)s[k];
            }
        }
        return;
    }
    // cvt role: one wave per row -> bf16 row + selfdot = W_r.x + b_l
    int wave = ((b - SPLIT_BLOCKS) * 256 + threadIdx.x) >> 6;
    int lane = threadIdx.x & 63;
    if (wave >= N_NODES) return;

    float2 x = ((const float2*)(X + (size_t)wave * D_IN))[lane];
    unsigned int packed = ((unsigned int)f32_to_bf16_rn(x.y) << 16)
                        |  (unsigned int)f32_to_bf16_rn(x.x);
    ((unsigned int*)(Xh + (size_t)wave * D_IN))[lane] = packed;

    float2 wr = ((const float2*)W_r)[lane];
    float acc = x.x * wr.x + x.y * wr.y;
#pragma unroll
    for (int off = 32; off; off >>= 1)
        acc += __shfl_down(acc, off);
    if (lane == 0)
        selfdot[wave] = acc + b_l[0];
}

// One block per 64-node bucket: LDS per-node segments, coalesced write-out.
__global__ __launch_bounds__(256) void k_build(
    const unsigned int* __restrict__ staging,
    const int*   __restrict__ gctr,
    int*         __restrict__ cnt,
    unsigned short* __restrict__ sorted16)
{
    __shared__ unsigned short lbuf[64 * CAP];   // 8 KB
    __shared__ int lcnt[64];
    int b   = blockIdx.x;        // bucket
    int tid = threadIdx.x;
    if (tid < 64) lcnt[tid] = 0;
    __syncthreads();

    int count = gctr[b];
    if (count > BCAP) count = BCAP;
    for (int i = tid; i < count; i += 256) {
        unsigned int rec = staging[(size_t)b * BCAP + i];
        int nlo = rec >> 16;
        int pos = atomicAdd(&lcnt[nlo], 1);
        if (pos < CAP)
            lbuf[nlo * CAP + pos] = (unsigned short)(rec & 0xffffu);
    }
    __syncthreads();

    int nodebase = b << 6;
    if (tid < 64) {
        int node = nodebase + tid;
        if (node < N_NODES) {
            int c = lcnt[tid];
            cnt[node] = c < CAP ? c : CAP;
        }
    }
    int nrows = N_NODES - nodebase;
    if (nrows > 64) nrows = 64;
    int tot32 = nrows * (CAP / 2);               // dwords to copy
    const unsigned int* lb32 = (const unsigned int*)lbuf;
    unsigned int* out32 = (unsigned int*)(sorted16 + (size_t)nodebase * CAP);
    for (int i = tid; i < tot32; i += 256)
        out32[i] = lb32[i];                      // garbage tails never read
}

#define GLOAD(uu, ss)  uu = Xu[(size_t)(ss) * 64 + lane];
#define GMAX(mm, uu)                                                  \
    {                                                                 \
        (mm).x = fmaxf((mm).x, __uint_as_float((uu) << 16));          \
        (mm).y = fmaxf((mm).y, __uint_as_float((uu) & 0xffff0000u));  \
    }
#define GATHER(mm, ss)                                                \
    { unsigned int u_; GLOAD(u_, ss) GMAX(mm, u_) }

// One wave per node. 16 gathers in flight (fold into m[8]), 8/4/2/1 tail.
__global__ __launch_bounds__(256) void k_agg(
    const unsigned short* __restrict__ Xh,
    const int*   __restrict__ cnt,
    const unsigned short* __restrict__ sorted16,
    const float* __restrict__ W_l,
    const float* __restrict__ selfdot,
    float*       __restrict__ out)
{
    int wave = (blockIdx.x * 256 + threadIdx.x) >> 6;
    int lane = threadIdx.x & 63;
    if (wave >= N_NODES) return;

    // independent loads -> both in flight together
    int n = cnt[wave];
    int sid = (int)sorted16[wave * CAP + lane];   // lanes >= n never consumed
    if (n > CAP) n = CAP;

    float2 wl = ((const float2*)W_l)[lane];   // hoisted: overlaps gather latency
    float sd  = selfdot[wave];

    const unsigned int* Xu = (const unsigned int*)Xh;
    float2 m[8];
#pragma unroll
    for (int k = 0; k < 8; ++k) m[k] = make_float2(-INFINITY, -INFINITY);

    int i = 0;
    for (; i + 16 <= n; i += 16) {
        int sr[16];
#pragma unroll
        for (int k = 0; k < 16; ++k) sr[k] = __shfl(sid, i + k);
        unsigned int u[16];
#pragma unroll
        for (int k = 0; k < 16; ++k) GLOAD(u[k], sr[k])   // 16 in flight
#pragma unroll
        for (int k = 0; k < 16; ++k) GMAX(m[k & 7], u[k])
    }
    if (i + 8 <= n) {
        int sr[8];
#pragma unroll
        for (int k = 0; k < 8; ++k) sr[k] = __shfl(sid, i + k);
        unsigned int u[8];
#pragma unroll
        for (int k = 0; k < 8; ++k) GLOAD(u[k], sr[k])
#pragma unroll
        for (int k = 0; k < 8; ++k) GMAX(m[k], u[k])
        i += 8;
    }
    if (i + 4 <= n) {
        int s0 = __shfl(sid, i + 0), s1 = __shfl(sid, i + 1);
        int s2 = __shfl(sid, i + 2), s3 = __shfl(sid, i + 3);
        GATHER(m[0], s0) GATHER(m[1], s1) GATHER(m[2], s2) GATHER(m[3], s3)
        i += 4;
    }
    if (i + 2 <= n) {
        int s0 = __shfl(sid, i + 0), s1 = __shfl(sid, i + 1);
        GATHER(m[0], s0) GATHER(m[1], s1)
        i += 2;
    }
    if (i < n) {
        int s0 = __shfl(sid, i);
        GATHER(m[0], s0)
    }
#pragma unroll
    for (int k = 4; k; k >>= 1)
#pragma unroll
        for (int j = 0; j < k; ++j) {
            m[j].x = fmaxf(m[j].x, m[j + k].x);
            m[j].y = fmaxf(m[j].y, m[j + k].y);
        }
    if (n == 0) { m[0].x = 0.0f; m[0].y = 0.0f; }   // segment_max empty fill

    float acc = m[0].x * wl.x + m[0].y * wl.y;
#pragma unroll
    for (int off = 32; off; off >>= 1)
        acc += __shfl_down(acc, off);
    if (lane == 0)
        out[wave] = acc + sd;
}

extern "C" void kernel_launch(void* const* d_in, const int* in_sizes, int n_in,
                              void* d_out, int out_size, void* d_ws, size_t ws_size,
                              hipStream_t stream)
{
    const float* X   = (const float*)d_in[0];   // [N_NODES, D_IN]
    const float* W_l = (const float*)d_in[1];   // [1, D_IN]
    const float* b_l = (const float*)d_in[2];   // [1]
    const float* W_r = (const float*)d_in[3];   // [1, D_IN]
    const int*   ei  = (const int*)d_in[4];     // [2, N_EDGES]
    const int*   src = ei;
    const int*   dst = ei + N_EDGES;

    int* gctr = (int*)d_ws;                                         // 4 KB (1024 ints)
    unsigned int* staging = (unsigned int*)(gctr + 1024);           // 4.0 MB
    int* cnt = (int*)(staging + (size_t)NBKT * BCAP);               // 200 KB
    unsigned short* sorted16 = (unsigned short*)(cnt + N_NODES);    // 6.4 MB
    unsigned short* Xh = sorted16 + (size_t)N_NODES * CAP;          // 12.8 MB
    float* selfdot = (float*)(Xh + (size_t)N_NODES * D_IN);         // 200 KB
    float* out = (float*)d_out;

    k_zero<<<(NBKT + 255) / 256, 256, 0, stream>>>(gctr);
    k_split_cvt<<<SPLIT_BLOCKS + CVT_BLOCKS, 256, 0, stream>>>(
        src, dst, gctr, staging, X, W_r, b_l, Xh, selfdot);
    k_build<<<NBKT, 256, 0, stream>>>(staging, gctr, cnt, sorted16);
    k_agg<<<(N_NODES * 64 + 255) / 256, 256, 0, stream>>>(
        Xh, cnt, sorted16, W_l, selfdot, out);
}

// Round 19
// 62.325 us; speedup vs baseline: 1.1113x; 1.0280x over previous
//
#include <hip/hip_runtime.h>

#define N_NODES 50000
#define N_EDGES 800000
#define D_IN    128
#define CAP     64      // max degree ~40 for Binomial(800k, 1/50k)

#define NBKT    782     // ceil(50000/64) buckets of 64 nodes (bucket = dst>>6)
#define BCAP    1280    // per-bucket staging cap (mean 1024, sd 32, +8 sigma)
#define EPT     16      // edges per thread in k_split
#define EPB     (256 * EPT)                        // 4096 edges per split block
#define SPLIT_BLOCKS ((N_EDGES + EPB - 1) / EPB)   // 196
#define CVT_BLOCKS   (N_NODES / 8)                 // 6250 (2 rows/wave, 4 waves/block)

// ---------------------------------------------------------------------------
// Round 19 = round 18 (64.1us best) + feeder efficiency:
//   1. cvt: float4 loads, 2 rows/wave, width-32 shfl reduce (half the blocks,
//      half the instructions per byte).
//   2. k_build: int4 LDS->global write-out.
//   3. k_agg: 32-bit gather addressing (drop 64-bit mul per gather).
//
// ws: gctr[1024] 4KB | staging[782*1280] u32 4MB | cnt[N] 200KB |
//     sorted16[N*CAP] u16 6.4MB | Xh[N*128] u16 12.8MB | selfdot[N] 200KB
// ---------------------------------------------------------------------------

__device__ __forceinline__ unsigned int f32_to_bf16_rn(float f) {
    unsigned int u = __float_as_uint(f);
    u += 0x7fffu + ((u >> 16) & 1u);      // round-to-nearest-even
    return u >> 16;
}

__global__ __launch_bounds__(256) void k_zero(int* __restrict__ gctr)
{
    int i = blockIdx.x * 256 + threadIdx.x;
    if (i < NBKT) gctr[i] = 0;
}

__global__ __launch_bounds__(256) void k_split_cvt(
    const int*   __restrict__ src,
    const int*   __restrict__ dst,
    int*         __restrict__ gctr,
    unsigned int* __restrict__ staging,
    const float* __restrict__ X,
    const float* __restrict__ W_r,
    const float* __restrict__ b_l,
    unsigned short* __restrict__ Xh,
    float*       __restrict__ selfdot)
{
    int b = blockIdx.x;
    if (b < SPLIT_BLOCKS) {
        __shared__ int hist[NBKT];
        __shared__ int base[NBKT];
        int tid = threadIdx.x;
        for (int i = tid; i < NBKT; i += 256) hist[i] = 0;
        __syncthreads();

        // int4 edge loads: block covers 1024 int4s (=4096 edges).
        int t[EPT], s[EPT], bk[EPT];
        bool ok[EPT];
        const int4* d4 = (const int4*)dst;
        const int4* s4 = (const int4*)src;
        int q0 = b * (EPB / 4) + tid;
#pragma unroll
        for (int k = 0; k < 4; ++k) {
            int q = q0 + (k << 8);                     // int4 index
            bool v = (q * 4) < N_EDGES;                // N_EDGES % 4 == 0
            int qc = v ? q : 0;
            int4 dv = d4[qc];
            int4 sv = s4[qc];
            t[k*4+0] = dv.x; t[k*4+1] = dv.y; t[k*4+2] = dv.z; t[k*4+3] = dv.w;
            s[k*4+0] = sv.x; s[k*4+1] = sv.y; s[k*4+2] = sv.z; s[k*4+3] = sv.w;
            ok[k*4+0] = ok[k*4+1] = ok[k*4+2] = ok[k*4+3] = v;
        }
#pragma unroll
        for (int k = 0; k < EPT; ++k) {
            bk[k] = t[k] >> 6;
            if (ok[k]) atomicAdd(&hist[bk[k]], 1);     // fire-and-forget LDS add
        }
        __syncthreads();
        for (int i = tid; i < NBKT; i += 256) {
            int h = hist[i];
            base[i] = h ? atomicAdd(&gctr[i], h) : 0;  // 1 global atomic/bucket
            hist[i] = 0;                               // reuse as cursor
        }
        __syncthreads();
#pragma unroll
        for (int k = 0; k < EPT; ++k) {
            if (ok[k]) {
                int pos = base[bk[k]] + atomicAdd(&hist[bk[k]], 1);
                if (pos < BCAP)
                    staging[(size_t)bk[k] * BCAP + pos] =
                        ((unsigned int)(t[k] & 63) << 16) | (unsigned int)s[k];
            }
        }
        return;
    }
    // cvt role: 2 rows per wave, float4 per lane (16B), width-32 reduce.
    int wave = ((b - SPLIT_BLOCKS) * 256 + threadIdx.x) >> 6;
    int lane = threadIdx.x & 63;
    int half = lane >> 5;            // 0 or 1
    int sub  = lane & 31;
    int row  = wave * 2 + half;
    if (row >= N_NODES) return;

    float4 x = ((const float4*)(X + (size_t)row * D_IN))[sub];
    unsigned int p0 = (f32_to_bf16_rn(x.y) << 16) | f32_to_bf16_rn(x.x);
    unsigned int p1 = (f32_to_bf16_rn(x.w) << 16) | f32_to_bf16_rn(x.z);
    ((uint2*)Xh)[row * 32 + sub] = make_uint2(p0, p1);

    float4 wr = ((const float4*)W_r)[sub];
    float acc = x.x * wr.x + x.y * wr.y + x.z * wr.z + x.w * wr.w;
#pragma unroll
    for (int off = 16; off; off >>= 1)
        acc += __shfl_down(acc, off, 32);
    if (sub == 0)
        selfdot[row] = acc + b_l[0];
}

// One block per 64-node bucket: LDS per-node segments, int4 write-out.
__global__ __launch_bounds__(256) void k_build(
    const unsigned int* __restrict__ staging,
    const int*   __restrict__ gctr,
    int*         __restrict__ cnt,
    unsigned short* __restrict__ sorted16)
{
    __shared__ __align__(16) unsigned short lbuf[64 * CAP];   // 8 KB
    __shared__ int lcnt[64];
    int b   = blockIdx.x;        // bucket
    int tid = threadIdx.x;
    if (tid < 64) lcnt[tid] = 0;
    __syncthreads();

    int count = gctr[b];
    if (count > BCAP) count = BCAP;
    for (int i = tid; i < count; i += 256) {
        unsigned int rec = staging[(size_t)b * BCAP + i];
        int nlo = rec >> 16;
        int pos = atomicAdd(&lcnt[nlo], 1);
        if (pos < CAP)
            lbuf[nlo * CAP + pos] = (unsigned short)(rec & 0xffffu);
    }
    __syncthreads();

    int nodebase = b << 6;
    if (tid < 64) {
        int node = nodebase + tid;
        if (node < N_NODES) {
            int c = lcnt[tid];
            cnt[node] = c < CAP ? c : CAP;
        }
    }
    int nrows = N_NODES - nodebase;
    if (nrows > 64) nrows = 64;
    int tot128 = nrows * (CAP / 8);              // int4s to copy (8 u16 each)
    const int4* lb128 = (const int4*)lbuf;
    int4* out128 = (int4*)(sorted16 + (size_t)nodebase * CAP);
    for (int i = tid; i < tot128; i += 256)
        out128[i] = lb128[i];                    // garbage tails never read
}

#define GLOAD(uu, ss)  uu = Xu[((unsigned)(ss) << 6) | (unsigned)lane];
#define GMAX(mm, uu)                                                  \
    {                                                                 \
        (mm).x = fmaxf((mm).x, __uint_as_float((uu) << 16));          \
        (mm).y = fmaxf((mm).y, __uint_as_float((uu) & 0xffff0000u));  \
    }
#define GATHER(mm, ss)                                                \
    { unsigned int u_; GLOAD(u_, ss) GMAX(mm, u_) }

// One wave per node. 16 gathers in flight (fold into m[8]), 8/4/2/1 tail.
__global__ __launch_bounds__(256) void k_agg(
    const unsigned short* __restrict__ Xh,
    const int*   __restrict__ cnt,
    const unsigned short* __restrict__ sorted16,
    const float* __restrict__ W_l,
    const float* __restrict__ selfdot,
    float*       __restrict__ out)
{
    int wave = (blockIdx.x * 256 + threadIdx.x) >> 6;
    int lane = threadIdx.x & 63;
    if (wave >= N_NODES) return;

    // independent loads -> both in flight together
    int n = cnt[wave];
    int sid = (int)sorted16[wave * CAP + lane];   // lanes >= n never consumed
    if (n > CAP) n = CAP;

    float2 wl = ((const float2*)W_l)[lane];   // hoisted: overlaps gather latency
    float sd  = selfdot[wave];

    const unsigned int* Xu = (const unsigned int*)Xh;
    float2 m[8];
#pragma unroll
    for (int k = 0; k < 8; ++k) m[k] = make_float2(-INFINITY, -INFINITY);

    int i = 0;
    for (; i + 16 <= n; i += 16) {
        int sr[16];
#pragma unroll
        for (int k = 0; k < 16; ++k) sr[k] = __shfl(sid, i + k);
        unsigned int u[16];
#pragma unroll
        for (int k = 0; k < 16; ++k) GLOAD(u[k], sr[k])   // 16 in flight
#pragma unroll
        for (int k = 0; k < 16; ++k) GMAX(m[k & 7], u[k])
    }
    if (i + 8 <= n) {
        int sr[8];
#pragma unroll
        for (int k = 0; k < 8; ++k) sr[k] = __shfl(sid, i + k);
        unsigned int u[8];
#pragma unroll
        for (int k = 0; k < 8; ++k) GLOAD(u[k], sr[k])
#pragma unroll
        for (int k = 0; k < 8; ++k) GMAX(m[k], u[k])
        i += 8;
    }
    if (i + 4 <= n) {
        int s0 = __shfl(sid, i + 0), s1 = __shfl(sid, i + 1);
        int s2 = __shfl(sid, i + 2), s3 = __shfl(sid, i + 3);
        GATHER(m[0], s0) GATHER(m[1], s1) GATHER(m[2], s2) GATHER(m[3], s3)
        i += 4;
    }
    if (i + 2 <= n) {
        int s0 = __shfl(sid, i + 0), s1 = __shfl(sid, i + 1);
        GATHER(m[0], s0) GATHER(m[1], s1)
        i += 2;
    }
    if (i < n) {
        int s0 = __shfl(sid, i);
        GATHER(m[0], s0)
    }
#pragma unroll
    for (int k = 4; k; k >>= 1)
#pragma unroll
        for (int j = 0; j < k; ++j) {
            m[j].x = fmaxf(m[j].x, m[j + k].x);
            m[j].y = fmaxf(m[j].y, m[j + k].y);
        }
    if (n == 0) { m[0].x = 0.0f; m[0].y = 0.0f; }   // segment_max empty fill

    float acc = m[0].x * wl.x + m[0].y * wl.y;
#pragma unroll
    for (int off = 32; off; off >>= 1)
        acc += __shfl_down(acc, off);
    if (lane == 0)
        out[wave] = acc + sd;
}

extern "C" void kernel_launch(void* const* d_in, const int* in_sizes, int n_in,
                              void* d_out, int out_size, void* d_ws, size_t ws_size,
                              hipStream_t stream)
{
    const float* X   = (const float*)d_in[0];   // [N_NODES, D_IN]
    const float* W_l = (const float*)d_in[1];   // [1, D_IN]
    const float* b_l = (const float*)d_in[2];   // [1]
    const float* W_r = (const float*)d_in[3];   // [1, D_IN]
    const int*   ei  = (const int*)d_in[4];     // [2, N_EDGES]
    const int*   src = ei;
    const int*   dst = ei + N_EDGES;

    int* gctr = (int*)d_ws;                                         // 4 KB (1024 ints)
    unsigned int* staging = (unsigned int*)(gctr + 1024);           // 4.0 MB
    int* cnt = (int*)(staging + (size_t)NBKT * BCAP);               // 200 KB
    unsigned short* sorted16 = (unsigned short*)(cnt + N_NODES);    // 6.4 MB
    unsigned short* Xh = sorted16 + (size_t)N_NODES * CAP;          // 12.8 MB
    float* selfdot = (float*)(Xh + (size_t)N_NODES * D_IN);         // 200 KB
    float* out = (float*)d_out;

    k_zero<<<(NBKT + 255) / 256, 256, 0, stream>>>(gctr);
    k_split_cvt<<<SPLIT_BLOCKS + CVT_BLOCKS, 256, 0, stream>>>(
        src, dst, gctr, staging, X, W_r, b_l, Xh, selfdot);
    k_build<<<NBKT, 256, 0, stream>>>(staging, gctr, cnt, sorted16);
    k_agg<<<(N_NODES * 64 + 255) / 256, 256, 0, stream>>>(
        Xh, cnt, sorted16, W_l, selfdot, out);
}

// Round 20
// 57.009 us; speedup vs baseline: 1.2149x; 1.0932x over previous
//
#include <hip/hip_runtime.h>

#define N_NODES 50000
#define N_EDGES 800000
#define D_IN    128
#define CAP     64      // max degree ~40 for Binomial(800k, 1/50k)

#define NBKT    782     // ceil(50000/64) buckets of 64 nodes (bucket = dst>>6)
#define BCAP    1280    // per-bucket staging cap (mean 1024, sd 32, +8 sigma)
#define EPT     16      // edges per thread in k_split
#define EPB     (256 * EPT)                        // 4096 edges per split block
#define SPLIT_BLOCKS ((N_EDGES + EPB - 1) / EPB)   // 196
#define CVT_BLOCKS   (N_NODES / 8)                 // 6250 (2 rows/wave)

// ---------------------------------------------------------------------------
// Round 20 = round 19 (62.3us best) + build/agg fusion done right:
//   k_bagg: 782 blocks x 1024 threads (16 waves x 4 nodes/wave = 12512 waves,
//   same wave-parallelism as the separate k_agg — round 16's 4-wave version
//   collapsed outstanding-miss count). Saves the 6.6MB sorted16/cnt
//   round-trip + one launch. Neighbor ids via LDS broadcast (no shfl).
//
// ws: gctr[1024] 4KB | staging[782*1280] u32 4MB | Xh[N*128] u16 12.8MB |
//     selfdot[N] f32 200KB
// ---------------------------------------------------------------------------

__device__ __forceinline__ unsigned int f32_to_bf16_rn(float f) {
    unsigned int u = __float_as_uint(f);
    u += 0x7fffu + ((u >> 16) & 1u);      // round-to-nearest-even
    return u >> 16;
}

__global__ __launch_bounds__(256) void k_zero(int* __restrict__ gctr)
{
    int i = blockIdx.x * 256 + threadIdx.x;
    if (i < NBKT) gctr[i] = 0;
}

__global__ __launch_bounds__(256) void k_split_cvt(
    const int*   __restrict__ src,
    const int*   __restrict__ dst,
    int*         __restrict__ gctr,
    unsigned int* __restrict__ staging,
    const float* __restrict__ X,
    const float* __restrict__ W_r,
    const float* __restrict__ b_l,
    unsigned short* __restrict__ Xh,
    float*       __restrict__ selfdot)
{
    int b = blockIdx.x;
    if (b < SPLIT_BLOCKS) {
        __shared__ int hist[NBKT];
        __shared__ int base[NBKT];
        int tid = threadIdx.x;
        for (int i = tid; i < NBKT; i += 256) hist[i] = 0;
        __syncthreads();

        int t[EPT], s[EPT], bk[EPT];
        bool ok[EPT];
        const int4* d4 = (const int4*)dst;
        const int4* s4 = (const int4*)src;
        int q0 = b * (EPB / 4) + tid;
#pragma unroll
        for (int k = 0; k < 4; ++k) {
            int q = q0 + (k << 8);                     // int4 index
            bool v = (q * 4) < N_EDGES;                // N_EDGES % 4 == 0
            int qc = v ? q : 0;
            int4 dv = d4[qc];
            int4 sv = s4[qc];
            t[k*4+0] = dv.x; t[k*4+1] = dv.y; t[k*4+2] = dv.z; t[k*4+3] = dv.w;
            s[k*4+0] = sv.x; s[k*4+1] = sv.y; s[k*4+2] = sv.z; s[k*4+3] = sv.w;
            ok[k*4+0] = ok[k*4+1] = ok[k*4+2] = ok[k*4+3] = v;
        }
#pragma unroll
        for (int k = 0; k < EPT; ++k) {
            bk[k] = t[k] >> 6;
            if (ok[k]) atomicAdd(&hist[bk[k]], 1);     // fire-and-forget LDS add
        }
        __syncthreads();
        for (int i = tid; i < NBKT; i += 256) {
            int h = hist[i];
            base[i] = h ? atomicAdd(&gctr[i], h) : 0;  // 1 global atomic/bucket
            hist[i] = 0;                               // reuse as cursor
        }
        __syncthreads();
#pragma unroll
        for (int k = 0; k < EPT; ++k) {
            if (ok[k]) {
                int pos = base[bk[k]] + atomicAdd(&hist[bk[k]], 1);
                if (pos < BCAP)
                    staging[(size_t)bk[k] * BCAP + pos] =
                        ((unsigned int)(t[k] & 63) << 16) | (unsigned int)s[k];
            }
        }
        return;
    }
    // cvt role: 2 rows per wave, float4 per lane (16B), width-32 reduce.
    int wave = ((b - SPLIT_BLOCKS) * 256 + threadIdx.x) >> 6;
    int lane = threadIdx.x & 63;
    int half = lane >> 5;            // 0 or 1
    int sub  = lane & 31;
    int row  = wave * 2 + half;
    if (row >= N_NODES) return;

    float4 x = ((const float4*)(X + (size_t)row * D_IN))[sub];
    unsigned int p0 = (f32_to_bf16_rn(x.y) << 16) | f32_to_bf16_rn(x.x);
    unsigned int p1 = (f32_to_bf16_rn(x.w) << 16) | f32_to_bf16_rn(x.z);
    ((uint2*)Xh)[row * 32 + sub] = make_uint2(p0, p1);

    float4 wr = ((const float4*)W_r)[sub];
    float acc = x.x * wr.x + x.y * wr.y + x.z * wr.z + x.w * wr.w;
#pragma unroll
    for (int off = 16; off; off >>= 1)
        acc += __shfl_down(acc, off, 32);
    if (sub == 0)
        selfdot[row] = acc + b_l[0];
}

#define GLOAD(uu, ss)  uu = Xu[((unsigned)(ss) << 6) | (unsigned)lane];
#define GMAX(mm, uu)                                                  \
    {                                                                 \
        (mm).x = fmaxf((mm).x, __uint_as_float((uu) << 16));          \
        (mm).y = fmaxf((mm).y, __uint_as_float((uu) & 0xffff0000u));  \
    }
#define GATHER(mm, ss)                                                \
    { unsigned int u_; GLOAD(u_, ss) GMAX(mm, u_) }

// Fused build+aggregate: one block per 64-node bucket, 1024 threads.
// Phase A: build per-node segments in LDS (8KB, LDS atomics).
// Phase B: 16 waves x 4 nodes; ids via LDS broadcast; 16-deep MLP gather.
__global__ __launch_bounds__(1024, 8) void k_bagg(
    const unsigned int* __restrict__ staging,
    const int*   __restrict__ gctr,
    const unsigned short* __restrict__ Xh,
    const float* __restrict__ W_l,
    const float* __restrict__ selfdot,
    float*       __restrict__ out)
{
    __shared__ unsigned short lbuf[64 * CAP];   // 8 KB
    __shared__ int lcnt[64];
    int b   = blockIdx.x;
    int tid = threadIdx.x;
    if (tid < 64) lcnt[tid] = 0;
    __syncthreads();

    // Phase A: scatter this bucket's records into LDS segments
    int count = gctr[b];
    if (count > BCAP) count = BCAP;
    for (int i = tid; i < count; i += 1024) {
        unsigned int rec = staging[(size_t)b * BCAP + i];
        int nlo = rec >> 16;
        int pos = atomicAdd(&lcnt[nlo], 1);
        if (pos < CAP)
            lbuf[nlo * CAP + pos] = (unsigned short)(rec & 0xffffu);
    }
    __syncthreads();

    // Phase B: 16 waves x 4 nodes each
    int wid  = tid >> 6;             // 0..15
    int lane = tid & 63;
    float2 wl = ((const float2*)W_l)[lane];
    const unsigned int* Xu = (const unsigned int*)Xh;
    int nodebase = b << 6;

#pragma unroll
    for (int j = 0; j < 4; ++j) {
        int li   = (wid << 2) + j;           // 0..63
        int node = nodebase + li;
        if (node >= N_NODES) continue;       // only last bucket
        float sd = selfdot[node];            // prefetch
        int n = lcnt[li];
        if (n > CAP) n = CAP;
        const unsigned short* seg = &lbuf[li * CAP];   // uniform -> broadcast

        float2 m[8];
#pragma unroll
        for (int k = 0; k < 8; ++k) m[k] = make_float2(-INFINITY, -INFINITY);

        int i = 0;
        for (; i + 16 <= n; i += 16) {
            int sr[16];
#pragma unroll
            for (int k = 0; k < 16; ++k) sr[k] = seg[i + k];
            unsigned int u[16];
#pragma unroll
            for (int k = 0; k < 16; ++k) GLOAD(u[k], sr[k])   // 16 in flight
#pragma unroll
            for (int k = 0; k < 16; ++k) GMAX(m[k & 7], u[k])
        }
        if (i + 8 <= n) {
            int sr[8];
#pragma unroll
            for (int k = 0; k < 8; ++k) sr[k] = seg[i + k];
            unsigned int u[8];
#pragma unroll
            for (int k = 0; k < 8; ++k) GLOAD(u[k], sr[k])
#pragma unroll
            for (int k = 0; k < 8; ++k) GMAX(m[k], u[k])
            i += 8;
        }
        if (i + 4 <= n) {
            GATHER(m[0], seg[i + 0]) GATHER(m[1], seg[i + 1])
            GATHER(m[2], seg[i + 2]) GATHER(m[3], seg[i + 3])
            i += 4;
        }
        if (i + 2 <= n) {
            GATHER(m[0], seg[i + 0]) GATHER(m[1], seg[i + 1])
            i += 2;
        }
        if (i < n) {
            GATHER(m[0], seg[i])
        }
#pragma unroll
        for (int k = 4; k; k >>= 1)
#pragma unroll
            for (int q = 0; q < k; ++q) {
                m[q].x = fmaxf(m[q].x, m[q + k].x);
                m[q].y = fmaxf(m[q].y, m[q + k].y);
            }
        if (n == 0) { m[0].x = 0.0f; m[0].y = 0.0f; }   // segment_max empty fill

        float acc = m[0].x * wl.x + m[0].y * wl.y;
#pragma unroll
        for (int off = 32; off; off >>= 1)
            acc += __shfl_down(acc, off);
        if (lane == 0)
            out[node] = acc + sd;
    }
}

extern "C" void kernel_launch(void* const* d_in, const int* in_sizes, int n_in,
                              void* d_out, int out_size, void* d_ws, size_t ws_size,
                              hipStream_t stream)
{
    const float* X   = (const float*)d_in[0];   // [N_NODES, D_IN]
    const float* W_l = (const float*)d_in[1];   // [1, D_IN]
    const float* b_l = (const float*)d_in[2];   // [1]
    const float* W_r = (const float*)d_in[3];   // [1, D_IN]
    const int*   ei  = (const int*)d_in[4];     // [2, N_EDGES]
    const int*   src = ei;
    const int*   dst = ei + N_EDGES;

    int* gctr = (int*)d_ws;                                         // 4 KB (1024 ints)
    unsigned int* staging = (unsigned int*)(gctr + 1024);           // 4.0 MB
    unsigned short* Xh = (unsigned short*)(staging + (size_t)NBKT * BCAP); // 12.8 MB
    float* selfdot = (float*)(Xh + (size_t)N_NODES * D_IN);         // 200 KB
    float* out = (float*)d_out;

    k_zero<<<(NBKT + 255) / 256, 256, 0, stream>>>(gctr);
    k_split_cvt<<<SPLIT_BLOCKS + CVT_BLOCKS, 256, 0, stream>>>(
        src, dst, gctr, staging, X, W_r, b_l, Xh, selfdot);
    k_bagg<<<NBKT, 1024, 0, stream>>>(staging, gctr, Xh, W_l, selfdot, out);
}